// Round 7
// baseline (626.628 us; speedup 1.0000x reference)
//
#include <hip/hip_runtime.h>

#define DIM 192
#define PLANE (DIM * DIM)              // 36864 floats per x-plane
#define VOL (PLANE * DIM)              // 7077888 floats per field (fits int)
#define DCH 3                          // i-chunk depth (R13 best: halved dispatch tail)
#define NCH (DIM / DCH)                // 64 chunks
#define GT 36                          // g-tiles per plane: 9216 float4 / 256
#define NBLK (GT * NCH * 2)            // 4608 blocks = 18/CU vs 8 resident

typedef float v4 __attribute__((ext_vector_type(4)));

__device__ __forceinline__ float4 ldg4(const float* __restrict__ p, int off) {
    return *(const float4*)(p + off);
}

// robust(x)^2 building block: r = m*(|x| - 0.5*m), m = min(|x|, 0.01)
__device__ __forceinline__ v4 robust4(v4 x) {
    v4 ax = __builtin_elementwise_abs(x);
    v4 m  = __builtin_elementwise_min(ax, (v4)(0.01f));
    return m * (ax - 0.5f * m);
}

__device__ __forceinline__ v4 sub_scale4(float4 a, float4 b, float s) {
    v4 r;
    r.x = (a.x - b.x) * s; r.y = (a.y - b.y) * s;
    r.z = (a.z - b.z) * s; r.w = (a.w - b.w) * s;
    return r;
}

__device__ __forceinline__ v4 zgrad4(float4 c, float lf, float rt,
                                     bool leftEdge, bool rightEdge) {
    v4 g;
    g.x = leftEdge  ? (c.y - c.x) : 0.5f * (c.y - lf);
    g.y = 0.5f * (c.z - c.x);
    g.z = 0.5f * (c.w - c.y);
    g.w = rightEdge ? (c.w - c.z) : 0.5f * (rt - c.z);
    return g;
}

// Module-persistent completion counter. Never reset: each run adds exactly
// NBLK, so "old % NBLK == NBLK-1" identifies the last block of THIS run.
// Immune to workspace poisoning and to graph replay (monotone growth).
__device__ unsigned int g_done = 0;

// R14: R13 body (shuffle z-halo, DCH=3, 4608 blocks) + fused finalize.
// The separate elastic_finalize launch cost a full device drain + launch
// (~4-6 us) for a 37 KB reduction. Now the last-finishing block performs
// the bitwise-identical reduction in-kernel. Cross-XCD visibility of
// partial[] via agent-scope atomic store/load (per-XCD L2s non-coherent).
__global__ __launch_bounds__(256, 4)
void elastic_main(const float* __restrict__ df, double* __restrict__ partial,
                  float* __restrict__ out) {
    const int tid  = threadIdx.x;              // 0..255
    const int lane = tid & 63;
    const int g    = blockIdx.x * 256 + tid;   // float4 index in plane, 0..9215
    const int g4   = g * 4;                    // float offset in plane
    const int gmod = g % 48;                   // float4 index within row
    const int j    = g / 48;
    const int i0   = blockIdx.y * DCH;
    const int b    = blockIdx.z;

    const float* __restrict__ u = df + (size_t)(b * 3 + 0) * VOL;
    const float* __restrict__ v = df + (size_t)(b * 3 + 1) * VOL;
    const float* __restrict__ w = df + (size_t)(b * 3 + 2) * VOL;

    const bool leftEdge  = (gmod == 0);
    const bool rightEdge = (gmod == 47);

    const int jp = (j < DIM - 1) ? j + 1 : j;
    const int jm = (j > 0) ? j - 1 : j;
    const float sy = ((jp - jm) == 2) ? 0.5f : 1.0f;
    const int yOfsP = jp * DIM + gmod * 4;     // float offset within plane
    const int yOfsM = jm * DIM + gmod * 4;

    // z-halo: lane0 needs element g4-1 (its lf), lane63 needs g4+4 (its rt)
    const bool doHalo = (lane == 0) || (lane == 63);
    const int hOfs = (lane == 0) ? (leftEdge ? g4 : g4 - 1)
                                 : (rightEdge ? g4 : g4 + 4);

    // rotation registers: center rows of planes max(i-1,0), i
    float4 um, vm, wm, uc, vc, wc;
    {
        const int im1 = (i0 > 0) ? i0 - 1 : 0;
        um = ldg4(u, im1 * PLANE + g4); vm = ldg4(v, im1 * PLANE + g4);
        wm = ldg4(w, im1 * PLANE + g4);
        uc = ldg4(u, i0 * PLANE + g4);  vc = ldg4(v, i0 * PLANE + g4);
        wc = ldg4(w, i0 * PLANE + g4);
    }

    v4 accA = (v4)(0.f);   // rtr^2 + rxx^2 + ryy^2 + rzz^2   (weight 0.5)
    v4 accB = (v4)(0.f);   // rxy^2 + rxz^2 + ryz^2           (weight 1.0)
    v4 accC = (v4)(0.f);   // relu(-jac)                      (weight 0.1)
    int oC = i0 * PLANE;                       // plane-i base (float offset)

    for (int ii = 0; ii < DCH; ++ii) {
        const int i = i0 + ii;
        const int oP = oC + ((i < DIM - 1) ? PLANE : 0);   // clamped i+1 plane
        const float sx = (i > 0 && i < DIM - 1) ? 0.5f : 1.0f;

        const float4 up  = ldg4(u, oP + g4);
        const float4 vp  = ldg4(v, oP + g4);
        const float4 wp  = ldg4(w, oP + g4);
        const float4 uyp = ldg4(u, oC + yOfsP);
        const float4 uym = ldg4(u, oC + yOfsM);
        const float4 vyp = ldg4(v, oC + yOfsP);
        const float4 vym = ldg4(v, oC + yOfsM);
        const float4 wyp = ldg4(w, oC + yOfsP);
        const float4 wym = ldg4(w, oC + yOfsM);

        float hu = 0.f, hv = 0.f, hw = 0.f;
        if (doHalo) {                           // 1 predicated dword load/field
            hu = u[oC + hOfs]; hv = v[oC + hOfs]; hw = w[oC + hOfs];
        }

        float ulf = __shfl_up(uc.w, 1);
        float vlf = __shfl_up(vc.w, 1);
        float wlf = __shfl_up(wc.w, 1);
        float urt = __shfl_down(uc.x, 1);
        float vrt = __shfl_down(vc.x, 1);
        float wrt = __shfl_down(wc.x, 1);
        if (lane == 0)  { ulf = hu; vlf = hv; wlf = hw; }
        if (lane == 63) { urt = hu; vrt = hv; wrt = hw; }

        const v4 du_dz = zgrad4(uc, ulf, urt, leftEdge, rightEdge);
        const v4 dv_dz = zgrad4(vc, vlf, vrt, leftEdge, rightEdge);
        const v4 dw_dz = zgrad4(wc, wlf, wrt, leftEdge, rightEdge);

        const v4 du_dx = sub_scale4(up, um, sx);
        const v4 dv_dx = sub_scale4(vp, vm, sx);
        const v4 dw_dx = sub_scale4(wp, wm, sx);
        const v4 du_dy = sub_scale4(uyp, uym, sy);
        const v4 dv_dy = sub_scale4(vyp, vym, sy);
        const v4 dw_dy = sub_scale4(wyp, wym, sy);

        // ---- packed per-voxel math over 4 voxels ----
        const v4 E_xy = 0.5f * (du_dy + dv_dx);
        const v4 E_xz = 0.5f * (du_dz + dw_dx);
        const v4 E_yz = 0.5f * (dv_dz + dw_dy);
        const v4 tr   = du_dx + dv_dy + dw_dz;

        const v4 rtr = robust4(tr);
        const v4 rxx = robust4(du_dx), ryy = robust4(dv_dy), rzz = robust4(dw_dz);
        const v4 rxy = robust4(E_xy),  rxz = robust4(E_xz),  ryz = robust4(E_yz);

        accA += rtr * rtr + rxx * rxx + ryy * ryy + rzz * rzz;
        accB += rxy * rxy + rxz * rxz + ryz * ryz;

        // Replicate the reference expression EXACTLY (not the true determinant).
        const v4 a11 = 1.0f + du_dx;
        const v4 a22 = 1.0f + dv_dy;
        const v4 a33 = 1.0f + dw_dz;
        const v4 a31 = 1.0f + dw_dx;   // note: reference uses (1+dw_dx) here
        const v4 jac = a11 * (a22 * a33 - dv_dz * dw_dy)
                     - du_dy * (dv_dx * a33 - dv_dz * a31)
                     + du_dz * (dv_dx * dw_dy - a22 * a31);
        accC += __builtin_elementwise_max(-jac, (v4)(0.f));

        // rotate planes
        um = uc; vm = vc; wm = wc;
        uc = up; vc = vp; wc = wp;
        oC += PLANE;
    }

    // final combine with folded weights
    const v4 tot4 = 0.5f * accA + accB + 0.1f * accC;
    float vsum = tot4.x + tot4.y + tot4.z + tot4.w;

    #pragma unroll
    for (int off = 32; off > 0; off >>= 1)
        vsum += __shfl_down(vsum, off, 64);

    __shared__ float wpart[4];
    __shared__ bool amLast;
    if ((tid & 63) == 0) wpart[tid >> 6] = vsum;
    __syncthreads();
    if (tid == 0) {
        const int blk = blockIdx.x + GT * (blockIdx.y + NCH * blockIdx.z);
        const double p = (double)wpart[0] + (double)wpart[1]
                       + (double)wpart[2] + (double)wpart[3];
        // agent-scope release store: visible across XCDs before the counter bump
        __hip_atomic_store(&partial[blk], p, __ATOMIC_RELEASE,
                           __HIP_MEMORY_SCOPE_AGENT);
        const unsigned old = __hip_atomic_fetch_add(&g_done, 1u, __ATOMIC_ACQ_REL,
                                                    __HIP_MEMORY_SCOPE_AGENT);
        amLast = ((old % NBLK) == (NBLK - 1));
    }
    __syncthreads();

    if (amLast) {
        // bitwise-identical to the old elastic_finalize reduction
        double s = 0.0;
        for (int idx = tid; idx < NBLK; idx += 256)
            s += __hip_atomic_load(&partial[idx], __ATOMIC_RELAXED,
                                   __HIP_MEMORY_SCOPE_AGENT);

        #pragma unroll
        for (int off = 32; off > 0; off >>= 1)
            s += __shfl_down(s, off, 64);

        __shared__ double dpart[4];
        if ((tid & 63) == 0) dpart[tid >> 6] = s;
        __syncthreads();
        if (tid == 0) {
            const double tot = dpart[0] + dpart[1] + dpart[2] + dpart[3];
            out[0] = (float)(tot * (1.0 / 14155776.0));
        }
    }
}

extern "C" void kernel_launch(void* const* d_in, const int* in_sizes, int n_in,
                              void* d_out, int out_size, void* d_ws, size_t ws_size,
                              hipStream_t stream) {
    const float* df = (const float*)d_in[0];
    double* partial = (double*)d_ws;   // NBLK doubles, plain stores (no init)
    float* out = (float*)d_out;

    dim3 grid(GT, NCH, 2);             // 4608 blocks = 18/CU (8 resident)
    elastic_main<<<grid, 256, 0, stream>>>(df, partial, out);
}

// Round 8
// 294.326 us; speedup vs baseline: 2.1290x; 2.1290x over previous
//
#include <hip/hip_runtime.h>

#define DIM 192
#define PLANE (DIM * DIM)              // 36864 floats per x-plane
#define VOL (PLANE * DIM)              // 7077888 floats per field (fits int)
#define DCH 3                          // i-chunk depth (R13 best: halved dispatch tail)
#define NCH (DIM / DCH)                // 64 chunks
#define GT 36                          // g-tiles per plane: 9216 float4 / 256
#define NBLK (GT * NCH * 2)            // 4608 blocks = 18/CU vs 8 resident

typedef float v4 __attribute__((ext_vector_type(4)));

__device__ __forceinline__ float4 ldg4(const float* __restrict__ p, int off) {
    return *(const float4*)(p + off);
}

// robust(x)^2 building block: r = m*(|x| - 0.5*m), m = min(|x|, 0.01)
__device__ __forceinline__ v4 robust4(v4 x) {
    v4 ax = __builtin_elementwise_abs(x);
    v4 m  = __builtin_elementwise_min(ax, (v4)(0.01f));
    return m * (ax - 0.5f * m);
}

__device__ __forceinline__ v4 sub_scale4(float4 a, float4 b, float s) {
    v4 r;
    r.x = (a.x - b.x) * s; r.y = (a.y - b.y) * s;
    r.z = (a.z - b.z) * s; r.w = (a.w - b.w) * s;
    return r;
}

__device__ __forceinline__ v4 zgrad4(float4 c, float lf, float rt,
                                     bool leftEdge, bool rightEdge) {
    v4 g;
    g.x = leftEdge  ? (c.y - c.x) : 0.5f * (c.y - lf);
    g.y = 0.5f * (c.z - c.x);
    g.z = 0.5f * (c.w - c.y);
    g.w = rightEdge ? (c.w - c.z) : 0.5f * (rt - c.z);
    return g;
}

// Module-persistent state. g_done is never reset (each run adds exactly NBLK,
// "old % NBLK == NBLK-1" marks this run's last block; monotone => immune to
// poisoning/replay). g_acc is read-and-reset by the last block via atomicExch,
// and stream ordering guarantees no future run adds before this kernel ends.
__device__ unsigned int g_done = 0;
__device__ double g_acc = 0.0;

// R15: R13 body (shuffle z-halo, DCH=3, 4608 blocks) + FENCE-FREE fused
// finalize. R14's failure mechanism: agent-scope RELEASE/ACQ_REL emitted
// buffer_wbl2/buffer_inv per block, disabling L2 for all concurrent blocks
// (462 us, 4.9% HBM BW, FETCH unchanged -- pure latency). Fix: reduction by
// plain device-scope atomicAdd RMWs only (executed at the coherent point,
// no cache maintenance), completion forced by a data dependency on the
// returned old value before the counter bump.
__global__ __launch_bounds__(256, 4)
void elastic_main(const float* __restrict__ df, double* __restrict__ partial,
                  float* __restrict__ out) {
    const int tid  = threadIdx.x;              // 0..255
    const int lane = tid & 63;
    const int g    = blockIdx.x * 256 + tid;   // float4 index in plane, 0..9215
    const int g4   = g * 4;                    // float offset in plane
    const int gmod = g % 48;                   // float4 index within row
    const int j    = g / 48;
    const int i0   = blockIdx.y * DCH;
    const int b    = blockIdx.z;

    const float* __restrict__ u = df + (size_t)(b * 3 + 0) * VOL;
    const float* __restrict__ v = df + (size_t)(b * 3 + 1) * VOL;
    const float* __restrict__ w = df + (size_t)(b * 3 + 2) * VOL;

    const bool leftEdge  = (gmod == 0);
    const bool rightEdge = (gmod == 47);

    const int jp = (j < DIM - 1) ? j + 1 : j;
    const int jm = (j > 0) ? j - 1 : j;
    const float sy = ((jp - jm) == 2) ? 0.5f : 1.0f;
    const int yOfsP = jp * DIM + gmod * 4;     // float offset within plane
    const int yOfsM = jm * DIM + gmod * 4;

    // z-halo: lane0 needs element g4-1 (its lf), lane63 needs g4+4 (its rt)
    const bool doHalo = (lane == 0) || (lane == 63);
    const int hOfs = (lane == 0) ? (leftEdge ? g4 : g4 - 1)
                                 : (rightEdge ? g4 : g4 + 4);

    // rotation registers: center rows of planes max(i-1,0), i
    float4 um, vm, wm, uc, vc, wc;
    {
        const int im1 = (i0 > 0) ? i0 - 1 : 0;
        um = ldg4(u, im1 * PLANE + g4); vm = ldg4(v, im1 * PLANE + g4);
        wm = ldg4(w, im1 * PLANE + g4);
        uc = ldg4(u, i0 * PLANE + g4);  vc = ldg4(v, i0 * PLANE + g4);
        wc = ldg4(w, i0 * PLANE + g4);
    }

    v4 accA = (v4)(0.f);   // rtr^2 + rxx^2 + ryy^2 + rzz^2   (weight 0.5)
    v4 accB = (v4)(0.f);   // rxy^2 + rxz^2 + ryz^2           (weight 1.0)
    v4 accC = (v4)(0.f);   // relu(-jac)                      (weight 0.1)
    int oC = i0 * PLANE;                       // plane-i base (float offset)

    for (int ii = 0; ii < DCH; ++ii) {
        const int i = i0 + ii;
        const int oP = oC + ((i < DIM - 1) ? PLANE : 0);   // clamped i+1 plane
        const float sx = (i > 0 && i < DIM - 1) ? 0.5f : 1.0f;

        const float4 up  = ldg4(u, oP + g4);
        const float4 vp  = ldg4(v, oP + g4);
        const float4 wp  = ldg4(w, oP + g4);
        const float4 uyp = ldg4(u, oC + yOfsP);
        const float4 uym = ldg4(u, oC + yOfsM);
        const float4 vyp = ldg4(v, oC + yOfsP);
        const float4 vym = ldg4(v, oC + yOfsM);
        const float4 wyp = ldg4(w, oC + yOfsP);
        const float4 wym = ldg4(w, oC + yOfsM);

        float hu = 0.f, hv = 0.f, hw = 0.f;
        if (doHalo) {                           // 1 predicated dword load/field
            hu = u[oC + hOfs]; hv = v[oC + hOfs]; hw = w[oC + hOfs];
        }

        float ulf = __shfl_up(uc.w, 1);
        float vlf = __shfl_up(vc.w, 1);
        float wlf = __shfl_up(wc.w, 1);
        float urt = __shfl_down(uc.x, 1);
        float vrt = __shfl_down(vc.x, 1);
        float wrt = __shfl_down(wc.x, 1);
        if (lane == 0)  { ulf = hu; vlf = hv; wlf = hw; }
        if (lane == 63) { urt = hu; vrt = hv; wrt = hw; }

        const v4 du_dz = zgrad4(uc, ulf, urt, leftEdge, rightEdge);
        const v4 dv_dz = zgrad4(vc, vlf, vrt, leftEdge, rightEdge);
        const v4 dw_dz = zgrad4(wc, wlf, wrt, leftEdge, rightEdge);

        const v4 du_dx = sub_scale4(up, um, sx);
        const v4 dv_dx = sub_scale4(vp, vm, sx);
        const v4 dw_dx = sub_scale4(wp, wm, sx);
        const v4 du_dy = sub_scale4(uyp, uym, sy);
        const v4 dv_dy = sub_scale4(vyp, vym, sy);
        const v4 dw_dy = sub_scale4(wyp, wym, sy);

        // ---- packed per-voxel math over 4 voxels ----
        const v4 E_xy = 0.5f * (du_dy + dv_dx);
        const v4 E_xz = 0.5f * (du_dz + dw_dx);
        const v4 E_yz = 0.5f * (dv_dz + dw_dy);
        const v4 tr   = du_dx + dv_dy + dw_dz;

        const v4 rtr = robust4(tr);
        const v4 rxx = robust4(du_dx), ryy = robust4(dv_dy), rzz = robust4(dw_dz);
        const v4 rxy = robust4(E_xy),  rxz = robust4(E_xz),  ryz = robust4(E_yz);

        accA += rtr * rtr + rxx * rxx + ryy * ryy + rzz * rzz;
        accB += rxy * rxy + rxz * rxz + ryz * ryz;

        // Replicate the reference expression EXACTLY (not the true determinant).
        const v4 a11 = 1.0f + du_dx;
        const v4 a22 = 1.0f + dv_dy;
        const v4 a33 = 1.0f + dw_dz;
        const v4 a31 = 1.0f + dw_dx;   // note: reference uses (1+dw_dx) here
        const v4 jac = a11 * (a22 * a33 - dv_dz * dw_dy)
                     - du_dy * (dv_dx * a33 - dv_dz * a31)
                     + du_dz * (dv_dx * dw_dy - a22 * a31);
        accC += __builtin_elementwise_max(-jac, (v4)(0.f));

        // rotate planes
        um = uc; vm = vc; wm = wc;
        uc = up; vc = vp; wc = wp;
        oC += PLANE;
    }

    // final combine with folded weights
    const v4 tot4 = 0.5f * accA + accB + 0.1f * accC;
    float vsum = tot4.x + tot4.y + tot4.z + tot4.w;

    #pragma unroll
    for (int off = 32; off > 0; off >>= 1)
        vsum += __shfl_down(vsum, off, 64);

    __shared__ float wpart[4];
    __shared__ bool amLast;
    if ((tid & 63) == 0) wpart[tid >> 6] = vsum;
    __syncthreads();
    if (tid == 0) {
        const double p = (double)wpart[0] + (double)wpart[1]
                       + (double)wpart[2] + (double)wpart[3];
        // device-scope f64 RMW at the coherent point -- NO cache maintenance
        const double oldacc = atomicAdd(&g_acc, p);
        // force the add to complete (s_waitcnt on the returned value) before
        // the counter bump; branch is never taken but unprovable-dead
        if (__builtin_expect(__double_as_longlong(oldacc) ==
                             (long long)0x7ff123456789abcdLL, 0))
            partial[0] = oldacc;               // keeps the dependency live
        const unsigned old = atomicAdd(&g_done, 1u);
        amLast = ((old % NBLK) == (NBLK - 1));
    }
    __syncthreads();

    if (amLast && tid == 0) {
        // read-and-reset in one RMW; all adds are at LLC by now (each writer
        // waited on its add before bumping the counter)
        const unsigned long long bits =
            atomicExch((unsigned long long*)&g_acc, 0ULL);
        const double tot = __longlong_as_double(bits);
        out[0] = (float)(tot * (1.0 / 14155776.0));
    }
}

extern "C" void kernel_launch(void* const* d_in, const int* in_sizes, int n_in,
                              void* d_out, int out_size, void* d_ws, size_t ws_size,
                              hipStream_t stream) {
    const float* df = (const float*)d_in[0];
    double* partial = (double*)d_ws;   // only used as a dead-store sink
    float* out = (float*)d_out;

    dim3 grid(GT, NCH, 2);             // 4608 blocks = 18/CU (8 resident)
    elastic_main<<<grid, 256, 0, stream>>>(df, partial, out);
}

// Round 9
// 234.311 us; speedup vs baseline: 2.6743x; 1.2561x over previous
//
#include <hip/hip_runtime.h>

#define DIM 192
#define PLANE (DIM * DIM)              // 36864 floats per x-plane
#define VOL (PLANE * DIM)              // 7077888 floats per field (fits int)
#define DCH 3                          // i-chunk depth (R13 best: halved dispatch tail)
#define NCH (DIM / DCH)                // 64 chunks
#define GT 36                          // g-tiles per plane: 9216 float4 / 256
#define NBLK (GT * NCH * 2)            // 4608 blocks = 18/CU vs 8 resident
#define NSLOT 64                       // reduction slots; NBLK/NSLOT = 72 adds/slot
#define QUOTA (NBLK / NSLOT)           // 72

typedef float v4 __attribute__((ext_vector_type(4)));

__device__ __forceinline__ float4 ldg4(const float* __restrict__ p, int off) {
    return *(const float4*)(p + off);
}

// robust(x)^2 building block: r = m*(|x| - 0.5*m), m = min(|x|, 0.01)
__device__ __forceinline__ v4 robust4(v4 x) {
    v4 ax = __builtin_elementwise_abs(x);
    v4 m  = __builtin_elementwise_min(ax, (v4)(0.01f));
    return m * (ax - 0.5f * m);
}

__device__ __forceinline__ v4 sub_scale4(float4 a, float4 b, float s) {
    v4 r;
    r.x = (a.x - b.x) * s; r.y = (a.y - b.y) * s;
    r.z = (a.z - b.z) * s; r.w = (a.w - b.w) * s;
    return r;
}

__device__ __forceinline__ v4 zgrad4(float4 c, float lf, float rt,
                                     bool leftEdge, bool rightEdge) {
    v4 g;
    g.x = leftEdge  ? (c.y - c.x) : 0.5f * (c.y - lf);
    g.y = 0.5f * (c.z - c.x);
    g.z = 0.5f * (c.w - c.y);
    g.w = rightEdge ? (c.w - c.z) : 0.5f * (rt - c.z);
    return g;
}

// Module-persistent reduction state (NOT in the poisoned workspace).
// g_slots: 64 f64 accumulators, one 64B cacheline each; read-and-reset by the
//   last block via atomicExch every run -> always 0 at run start.
// g_cnt1: per-slot completion counters (64B-padded). Monotone; each run adds
//   exactly QUOTA per slot, so "old % QUOTA == QUOTA-1" marks the slot's last
//   block of THIS run. g_cnt2: slot-finisher counter, 64 bumps/run.
__device__ unsigned long long g_slots[NSLOT * 8];   // zero-init at module load
__device__ unsigned int       g_cnt1[NSLOT * 16];
__device__ unsigned int       g_cnt2 = 0;

// R16: exact R13 body (shuffle z-halo, DCH=3, 4608 blocks, 239.2us proven)
// + fused finalize, 3rd attempt. R14 failed via per-block agent-scope fences
// (L2 writeback/invalidate storms, 462us). R15 failed via 4608 RMWs on ONE
// f64 address (LLC atomic oversubscription: arrivals ~7.6ns apart vs >=20ns
// per contended CAS-loop op -> ~95us queueing, 132us). R16 spreads the adds
// over 64 padded slots (72 adds/slot, ~490ns apart -> no queue), two-level
// last-block detection, ordering by returned-value data deps only (returning
// atomics retire at LLC completion). No fences anywhere.
__global__ __launch_bounds__(256, 4)
void elastic_main(const float* __restrict__ df, float* __restrict__ out) {
    const int tid  = threadIdx.x;              // 0..255
    const int lane = tid & 63;
    const int g    = blockIdx.x * 256 + tid;   // float4 index in plane, 0..9215
    const int g4   = g * 4;                    // float offset in plane
    const int gmod = g % 48;                   // float4 index within row
    const int j    = g / 48;
    const int i0   = blockIdx.y * DCH;
    const int b    = blockIdx.z;

    const float* __restrict__ u = df + (size_t)(b * 3 + 0) * VOL;
    const float* __restrict__ v = df + (size_t)(b * 3 + 1) * VOL;
    const float* __restrict__ w = df + (size_t)(b * 3 + 2) * VOL;

    const bool leftEdge  = (gmod == 0);
    const bool rightEdge = (gmod == 47);

    const int jp = (j < DIM - 1) ? j + 1 : j;
    const int jm = (j > 0) ? j - 1 : j;
    const float sy = ((jp - jm) == 2) ? 0.5f : 1.0f;
    const int yOfsP = jp * DIM + gmod * 4;     // float offset within plane
    const int yOfsM = jm * DIM + gmod * 4;

    // z-halo: lane0 needs element g4-1 (its lf), lane63 needs g4+4 (its rt)
    const bool doHalo = (lane == 0) || (lane == 63);
    const int hOfs = (lane == 0) ? (leftEdge ? g4 : g4 - 1)
                                 : (rightEdge ? g4 : g4 + 4);

    // rotation registers: center rows of planes max(i-1,0), i
    float4 um, vm, wm, uc, vc, wc;
    {
        const int im1 = (i0 > 0) ? i0 - 1 : 0;
        um = ldg4(u, im1 * PLANE + g4); vm = ldg4(v, im1 * PLANE + g4);
        wm = ldg4(w, im1 * PLANE + g4);
        uc = ldg4(u, i0 * PLANE + g4);  vc = ldg4(v, i0 * PLANE + g4);
        wc = ldg4(w, i0 * PLANE + g4);
    }

    v4 accA = (v4)(0.f);   // rtr^2 + rxx^2 + ryy^2 + rzz^2   (weight 0.5)
    v4 accB = (v4)(0.f);   // rxy^2 + rxz^2 + ryz^2           (weight 1.0)
    v4 accC = (v4)(0.f);   // relu(-jac)                      (weight 0.1)
    int oC = i0 * PLANE;                       // plane-i base (float offset)

    for (int ii = 0; ii < DCH; ++ii) {
        const int i = i0 + ii;
        const int oP = oC + ((i < DIM - 1) ? PLANE : 0);   // clamped i+1 plane
        const float sx = (i > 0 && i < DIM - 1) ? 0.5f : 1.0f;

        const float4 up  = ldg4(u, oP + g4);
        const float4 vp  = ldg4(v, oP + g4);
        const float4 wp  = ldg4(w, oP + g4);
        const float4 uyp = ldg4(u, oC + yOfsP);
        const float4 uym = ldg4(u, oC + yOfsM);
        const float4 vyp = ldg4(v, oC + yOfsP);
        const float4 vym = ldg4(v, oC + yOfsM);
        const float4 wyp = ldg4(w, oC + yOfsP);
        const float4 wym = ldg4(w, oC + yOfsM);

        float hu = 0.f, hv = 0.f, hw = 0.f;
        if (doHalo) {                           // 1 predicated dword load/field
            hu = u[oC + hOfs]; hv = v[oC + hOfs]; hw = w[oC + hOfs];
        }

        float ulf = __shfl_up(uc.w, 1);
        float vlf = __shfl_up(vc.w, 1);
        float wlf = __shfl_up(wc.w, 1);
        float urt = __shfl_down(uc.x, 1);
        float vrt = __shfl_down(vc.x, 1);
        float wrt = __shfl_down(wc.x, 1);
        if (lane == 0)  { ulf = hu; vlf = hv; wlf = hw; }
        if (lane == 63) { urt = hu; vrt = hv; wrt = hw; }

        const v4 du_dz = zgrad4(uc, ulf, urt, leftEdge, rightEdge);
        const v4 dv_dz = zgrad4(vc, vlf, vrt, leftEdge, rightEdge);
        const v4 dw_dz = zgrad4(wc, wlf, wrt, leftEdge, rightEdge);

        const v4 du_dx = sub_scale4(up, um, sx);
        const v4 dv_dx = sub_scale4(vp, vm, sx);
        const v4 dw_dx = sub_scale4(wp, wm, sx);
        const v4 du_dy = sub_scale4(uyp, uym, sy);
        const v4 dv_dy = sub_scale4(vyp, vym, sy);
        const v4 dw_dy = sub_scale4(wyp, wym, sy);

        // ---- packed per-voxel math over 4 voxels ----
        const v4 E_xy = 0.5f * (du_dy + dv_dx);
        const v4 E_xz = 0.5f * (du_dz + dw_dx);
        const v4 E_yz = 0.5f * (dv_dz + dw_dy);
        const v4 tr   = du_dx + dv_dy + dw_dz;

        const v4 rtr = robust4(tr);
        const v4 rxx = robust4(du_dx), ryy = robust4(dv_dy), rzz = robust4(dw_dz);
        const v4 rxy = robust4(E_xy),  rxz = robust4(E_xz),  ryz = robust4(E_yz);

        accA += rtr * rtr + rxx * rxx + ryy * ryy + rzz * rzz;
        accB += rxy * rxy + rxz * rxz + ryz * ryz;

        // Replicate the reference expression EXACTLY (not the true determinant).
        const v4 a11 = 1.0f + du_dx;
        const v4 a22 = 1.0f + dv_dy;
        const v4 a33 = 1.0f + dw_dz;
        const v4 a31 = 1.0f + dw_dx;   // note: reference uses (1+dw_dx) here
        const v4 jac = a11 * (a22 * a33 - dv_dz * dw_dy)
                     - du_dy * (dv_dx * a33 - dv_dz * a31)
                     + du_dz * (dv_dx * dw_dy - a22 * a31);
        accC += __builtin_elementwise_max(-jac, (v4)(0.f));

        // rotate planes
        um = uc; vm = vc; wm = wc;
        uc = up; vc = vp; wc = wp;
        oC += PLANE;
    }

    // final combine with folded weights
    const v4 tot4 = 0.5f * accA + accB + 0.1f * accC;
    float vsum = tot4.x + tot4.y + tot4.z + tot4.w;

    #pragma unroll
    for (int off = 32; off > 0; off >>= 1)
        vsum += __shfl_down(vsum, off, 64);

    __shared__ float wpart[4];
    __shared__ bool amLast;
    if ((tid & 63) == 0) wpart[tid >> 6] = vsum;
    __syncthreads();
    if (tid == 0) {
        const int blk = blockIdx.x + GT * (blockIdx.y + NCH * blockIdx.z);
        const int sid = blk & (NSLOT - 1);     // exactly QUOTA blocks per slot
        const double p = (double)wpart[0] + (double)wpart[1]
                       + (double)wpart[2] + (double)wpart[3];

        // slot accumulate: returning f64 RMW; consume the return value so the
        // op is complete at the LLC before the counter bump issues
        const double oldv = atomicAdd((double*)&g_slots[sid * 8], p);
        asm volatile("" :: "v"(oldv));         // data-dep barrier, no fence

        bool last = false;
        const unsigned c1 = atomicAdd(&g_cnt1[sid * 16], 1u);
        if ((c1 % QUOTA) == (QUOTA - 1)) {     // last block of this slot
            const unsigned c2 = atomicAdd(&g_cnt2, 1u);
            last = ((c2 & (NSLOT - 1)) == (NSLOT - 1));   // last slot done
        }
        amLast = last;
    }
    __syncthreads();

    if (amLast && tid < NSLOT) {
        // read-and-reset each slot in one RMW at the coherent point;
        // resets state for the next run (stream-ordered, so safe)
        const unsigned long long bits = atomicExch(&g_slots[tid * 8], 0ULL);
        double s = __longlong_as_double(bits);

        #pragma unroll
        for (int off = 32; off > 0; off >>= 1)
            s += __shfl_down(s, off, 64);

        if (tid == 0)
            out[0] = (float)(s * (1.0 / 14155776.0));
    }
}

extern "C" void kernel_launch(void* const* d_in, const int* in_sizes, int n_in,
                              void* d_out, int out_size, void* d_ws, size_t ws_size,
                              hipStream_t stream) {
    const float* df = (const float*)d_in[0];
    float* out = (float*)d_out;
    (void)d_ws; (void)ws_size;

    dim3 grid(GT, NCH, 2);             // 4608 blocks = 18/CU (8 resident)
    elastic_main<<<grid, 256, 0, stream>>>(df, out);
}